// Round 1
// baseline (58.200 us; speedup 1.0000x reference)
//
#include <hip/hip_runtime.h>

#define HH 128
#define WW 128
#define CC 64
#define KDIM 16

// Block: 256 threads = 4 waves.
//   lane = tid & 63 -> pixel within a 16(w) x 4(h) tile
//   g    = tid >> 6 -> wave role: phase1 computes k[d] for d in [4g,4g+4),
//                      phase2 handles channels c in [16g,16g+16)
// Grid: (W/16, H/4, B) = (8, 32, 4) = 1024 blocks.
__global__ __launch_bounds__(256, 4) void gatev_fused(
    const float* __restrict__ x, const float* __restrict__ y,
    const float* __restrict__ z,
    const float* __restrict__ Wq, const float* __restrict__ bq,
    const float* __restrict__ Wk, const float* __restrict__ bk,
    const float* __restrict__ wv, const float* __restrict__ bv,
    float* __restrict__ out)
{
    __shared__ float k_lds[64][16];   // [pixel][d]  4 KB

    const int tid  = threadIdx.x;
    const int g    = tid >> 6;
    const int lane = tid & 63;
    const int px   = lane & 15, py = lane >> 4;
    const int b    = blockIdx.z;
    const int h    = blockIdx.y * 4 + py;
    const int w    = blockIdx.x * 16 + px;
    const int pix  = h * WW + w;
    const int HW   = HH * WW;

    // 9 neighbor offsets (clamped, always in-bounds) + zero-pad masks
    int   off[9];
    float msk[9];
#pragma unroll
    for (int t = 0; t < 9; ++t) {
        const int dy = t / 3 - 1, dx = t % 3 - 1;
        const int hh = h + dy, ww = w + dx;
        const bool ok = (hh >= 0) && (hh < HH) && (ww >= 0) && (ww < WW);
        const int hc = min(max(hh, 0), HH - 1);
        const int wc = min(max(ww, 0), WW - 1);
        off[t] = hc * WW + wc;
        msk[t] = ok ? 1.0f : 0.0f;
    }

    // ---------------- phase 1: k = relu(conv3x3(x) + bk), 4 d's per wave ----
    const int d0 = g * 4;
    // wave-uniform base index into Wk for this wave's d-range
    const int wb0 = __builtin_amdgcn_readfirstlane(d0 * CC * 9);

    float acc0 = 0.f, acc1 = 0.f, acc2 = 0.f, acc3 = 0.f;
    const float* xb = x + (size_t)(b * CC) * HW;

    for (int c = 0; c < CC; ++c) {
        const float* xc = xb + c * HW;
        float xv[9];
#pragma unroll
        for (int t = 0; t < 9; ++t) xv[t] = xc[off[t]] * msk[t];
        const float* wp = Wk + wb0 + c * 9;   // uniform -> s_load weights
#pragma unroll
        for (int t = 0; t < 9; ++t) {
            acc0 = fmaf(wp[t],        xv[t], acc0);
            acc1 = fmaf(wp[576 + t],  xv[t], acc1);
            acc2 = fmaf(wp[1152 + t], xv[t], acc2);
            acc3 = fmaf(wp[1728 + t], xv[t], acc3);
        }
    }
    {
        const int du = __builtin_amdgcn_readfirstlane(d0);
        float4 kk;
        kk.x = fmaxf(acc0 + bk[du + 0], 0.f);
        kk.y = fmaxf(acc1 + bk[du + 1], 0.f);
        kk.z = fmaxf(acc2 + bk[du + 2], 0.f);
        kk.w = fmaxf(acc3 + bk[du + 3], 0.f);
        *(float4*)&k_lds[lane][d0] = kk;
    }
    __syncthreads();

    // ---------------- phase 2: q, v, softmax-attention, 16 c's per wave -----
    float kreg[16];
#pragma unroll
    for (int t = 0; t < 4; ++t) {
        const float4 kk = *(const float4*)&k_lds[lane][t * 4];
        kreg[t * 4 + 0] = kk.x;
        kreg[t * 4 + 1] = kk.y;
        kreg[t * 4 + 2] = kk.z;
        kreg[t * 4 + 3] = kk.w;
    }

    float wvr[16], bvr[16];
#pragma unroll
    for (int d = 0; d < KDIM; ++d) { wvr[d] = wv[d]; bvr[d] = bv[d]; }

    const int c0u = __builtin_amdgcn_readfirstlane(g * 16);
    const float* yb = y + (size_t)(b * CC) * HW;
    const float* zb = z + (size_t)(b * CC) * HW;
    float*       ob = out + (size_t)(b * CC) * HW;

    for (int ci = 0; ci < 16; ++ci) {
        const int c = c0u + ci;                 // wave-uniform
        const float* yc = yb + c * HW;
        const float* wq = Wq + c * 9;           // uniform -> s_load

        float q = 0.f;
#pragma unroll
        for (int t = 0; t < 9; ++t)
            q = fmaf(wq[t], yc[off[t]] * msk[t], q);
        q = fmaxf(q + bq[c], 0.f);

        const float zv = zb[c * HW + pix];

        // scores s_d = q*k_d >= 0 and bounded (~<=20): no max-subtraction needed
        float num = 0.f, den = 0.f;
#pragma unroll
        for (int d = 0; d < KDIM; ++d) {
            const float e = __expf(q * kreg[d]);
            const float v = fmaxf(fmaf(zv, wvr[d], bvr[d]), 0.f);
            num = fmaf(e, v, num);
            den += e;
        }
        ob[c * HW + pix] = __fdividef(num, den);
    }
}

extern "C" void kernel_launch(void* const* d_in, const int* in_sizes, int n_in,
                              void* d_out, int out_size, void* d_ws, size_t ws_size,
                              hipStream_t stream) {
    const float* x  = (const float*)d_in[0];
    const float* y  = (const float*)d_in[1];
    const float* z  = (const float*)d_in[2];
    const float* Wq = (const float*)d_in[3];
    const float* bq = (const float*)d_in[4];
    const float* Wk = (const float*)d_in[5];
    const float* bk = (const float*)d_in[6];
    const float* wv = (const float*)d_in[7];
    const float* bv = (const float*)d_in[8];
    float* out = (float*)d_out;

    dim3 grid(WW / 16, HH / 4, 4);   // (8, 32, 4)
    dim3 block(256);
    hipLaunchKernelGGL(gatev_fused, grid, block, 0, stream,
                       x, y, z, Wq, bq, Wk, bk, wv, bv, out);
}